// Round 4
// baseline (323.201 us; speedup 1.0000x reference)
//
#include <hip/hip_runtime.h>
#include <math.h>

// InfoNCE, exact JAX threefry2x32 negative-sampling reproduction.
// I=4096, E=16384, D=64.
//
// R4: R3's finalize was 190us with VALUBusy 6% -- a same-address
// atomicAdd(double) CAS-retry storm from 4096 light blocks arriving at
// once. Replace global atomics with per-row loss array + deterministic
// tree-reduce kernel. finalize -> 128 threads, item-norm hoisted.

constexpr int D      = 64;
constexpr int PCAP   = 96;    // num_pos ~ Binom(16384,.002): mean 33
constexpr int CCAP   = 192;   // bin-0 count ~ Binom(16384,1/256): mean 64
constexpr int SELCAP = 128;   // k <= npos <= PCAP

typedef int int4v __attribute__((ext_vector_type(4)));

// JAX threefry2x32, key = (0, 42) from jax.random.key(42).
__device__ __forceinline__ void threefry2x32(unsigned x0, unsigned x1,
                                             unsigned& o0, unsigned& o1) {
  const unsigned ks0 = 0u;
  const unsigned ks1 = 42u;
  const unsigned ks2 = 0x1BD11BDAu ^ 0u ^ 42u;
  x0 += ks0; x1 += ks1;
#define TF_R(r) { x0 += x1; x1 = (x1 << (r)) | (x1 >> (32 - (r))); x1 ^= x0; }
  TF_R(13) TF_R(15) TF_R(26) TF_R(6)
  x0 += ks1; x1 += ks2 + 1u;
  TF_R(17) TF_R(29) TF_R(16) TF_R(24)
  x0 += ks2; x1 += ks0 + 2u;
  TF_R(13) TF_R(15) TF_R(26) TF_R(6)
  x0 += ks0; x1 += ks1 + 3u;
  TF_R(17) TF_R(29) TF_R(16) TF_R(24)
  x0 += ks1; x1 += ks2 + 4u;
  TF_R(13) TF_R(15) TF_R(26) TF_R(6)
  x0 += ks2; x1 += ks0 + 5u;
#undef TF_R
  o0 = x0; o1 = x1;
}

__device__ __forceinline__ float dot_sim(const float* __restrict__ ent, int e,
                                         const float* itemn) {
  const float4* er = (const float4*)(ent + ((size_t)e << 6));
  float dot = 0.f, ss = 0.f;
#pragma unroll
  for (int q = 0; q < 16; ++q) {
    float4 f = er[q];
    dot += itemn[4 * q + 0] * f.x + itemn[4 * q + 1] * f.y +
           itemn[4 * q + 2] * f.z + itemn[4 * q + 3] * f.w;
    ss += f.x * f.x + f.y * f.y + f.z * f.z + f.w * f.w;
  }
  return dot * (1.0f / sqrtf(ss));
}

// 128-thread (2-wave) block reductions
__device__ __forceinline__ float bmax128(float v, float* w2, int t) {
#pragma unroll
  for (int off = 32; off; off >>= 1) v = fmaxf(v, __shfl_xor(v, off, 64));
  __syncthreads();
  if ((t & 63) == 0) w2[t >> 6] = v;
  __syncthreads();
  return fmaxf(w2[0], w2[1]);
}
__device__ __forceinline__ float bsum128(float v, float* w2, int t) {
#pragma unroll
  for (int off = 32; off; off >>= 1) v += __shfl_xor(v, off, 64);
  __syncthreads();
  if ((t & 63) == 0) w2[t >> 6] = v;
  __syncthreads();
  return w2[0] + w2[1];
}

// ---------------- workspace-based fast path ----------------

__global__ __launch_bounds__(256) void ws_zero(int* pos_cnt, int* cand_cnt,
                                               float* loss, int I) {
  int t = blockIdx.x * 256 + threadIdx.x;
  if (t < I) { pos_cnt[t] = 0; cand_cnt[t] = 0; loss[t] = 0.f; }
}

// Heterogeneous dispatch: blockIdx%3 in {0,1} -> pos-extract (memory-bound),
// ==2 -> cand-gen (pure VALU, no memory input). Interleaving mixes roles per CU.
__global__ __launch_bounds__(256) void phase1(
    const int* __restrict__ adj, int I, int E,
    int* __restrict__ pos_cnt, int* __restrict__ pos_idx,
    int* __restrict__ cand_cnt, int* __restrict__ cand_idx,
    unsigned* __restrict__ cand_key) {
  const int t = threadIdx.x;
  const int r3 = blockIdx.x % 3;
  const int g  = blockIdx.x / 3;

  if (r3 < 2) {
    // ---- positive extraction for row (2g + r3): pure adj stream ----
    const int row = g * 2 + r3;
    __shared__ int s_np;
    __shared__ int s_pos[PCAP];
    if (t == 0) s_np = 0;
    __syncthreads();
    const int4v* a = (const int4v*)(adj + (size_t)row * E);
    const int nvec = E >> 2;
    for (int v = t; v < nvec; v += 256) {
      int4v x = __builtin_nontemporal_load(&a[v]);  // one-shot stream
      int e0 = v * 4;
      if (x.x > 0) { int s = atomicAdd(&s_np, 1); if (s < PCAP) s_pos[s] = e0; }
      if (x.y > 0) { int s = atomicAdd(&s_np, 1); if (s < PCAP) s_pos[s] = e0 + 1; }
      if (x.z > 0) { int s = atomicAdd(&s_np, 1); if (s < PCAP) s_pos[s] = e0 + 2; }
      if (x.w > 0) { int s = atomicAdd(&s_np, 1); if (s < PCAP) s_pos[s] = e0 + 3; }
    }
    __syncthreads();
    const int np = s_np;  // true count; >PCAP triggers finalize fallback
    if (t == 0) pos_cnt[row] = np;
    const int npc = min(np, PCAP);
    for (int i = t; i < npc; i += 256) pos_idx[(size_t)row * PCAP + i] = s_pos[i];
  } else {
    // ---- candidate gen for row pair (g, g+I/2): NO memory input ----
    const int iA = g;
    const unsigned HALF = (unsigned)(I >> 1) * (unsigned)E;  // 2^25
    const unsigned base = (unsigned)iA * (unsigned)E;
    __shared__ int s_nc[2];
    __shared__ int s_ci[2][CCAP];
    __shared__ unsigned s_ck[2][CCAP];
    if (t < 2) s_nc[t] = 0;
    __syncthreads();
#define CAPP(bits, half, ee)                                              \
    if (((bits) >> 24) == 0u) {                                           \
      int s_ = atomicAdd(&s_nc[half], 1);                                 \
      if (s_ < CCAP) { s_ci[half][s_] = (int)(ee); s_ck[half][s_] = (bits) >> 9; } \
    }
    for (int it = 0; it < 16; ++it) {
      const unsigned e0 = (unsigned)(it * 1024 + t);
      unsigned a0, a1, b0, b1, c0, c1, d0, d1;
      threefry2x32(base + e0,       base + e0 + HALF,       a0, a1);
      threefry2x32(base + e0 + 256, base + e0 + 256 + HALF, b0, b1);
      threefry2x32(base + e0 + 512, base + e0 + 512 + HALF, c0, c1);
      threefry2x32(base + e0 + 768, base + e0 + 768 + HALF, d0, d1);
      CAPP(a0, 0, e0)       CAPP(a1, 1, e0)
      CAPP(b0, 0, e0 + 256) CAPP(b1, 1, e0 + 256)
      CAPP(c0, 0, e0 + 512) CAPP(c1, 1, e0 + 512)
      CAPP(d0, 0, e0 + 768) CAPP(d1, 1, e0 + 768)
    }
#undef CAPP
    __syncthreads();
    const int rowA = iA, rowB = iA + (I >> 1);
    const int ncA = s_nc[0], ncB = s_nc[1];
    if (t == 0) { cand_cnt[rowA] = ncA; cand_cnt[rowB] = ncB; }
    const int ncAc = min(ncA, CCAP), ncBc = min(ncB, CCAP);
    for (int i = t; i < ncAc; i += 256) {
      cand_idx[(size_t)rowA * CCAP + i] = s_ci[0][i];
      cand_key[(size_t)rowA * CCAP + i] = s_ck[0][i];
    }
    for (int i = t; i < ncBc; i += 256) {
      cand_idx[(size_t)rowB * CCAP + i] = s_ci[1][i];
      cand_key[(size_t)rowB * CCAP + i] = s_ck[1][i];
    }
  }
}

// One 128-thread block per row: filter + exact rank + dots + per-row loss.
// NO global atomics (R3's 4096-block same-address f64 CAS storm was 190us).
__global__ __launch_bounds__(128) void finalize(
    const float* __restrict__ item, const float* __restrict__ ent,
    const int* __restrict__ adj, int I, int E,
    const int* __restrict__ pos_cnt, const int* __restrict__ pos_idx,
    const int* __restrict__ cand_cnt, const int* __restrict__ cand_idx,
    const unsigned* __restrict__ cand_key,
    float* __restrict__ loss) {
  const int row = blockIdx.x;
  const int t = threadIdx.x;
  const int npos = pos_cnt[row];
  if (npos == 0) return;
  const int k = min(npos, E - npos);  // == npos here

  __shared__ int s_pos[PCAP];
  __shared__ int s_ci[CCAP];
  __shared__ unsigned s_ck[CCAP];
  __shared__ int s_sel[SELCAP];
  __shared__ int s_hist[256];
  __shared__ float s_itemn[D];
  __shared__ float s_w2[2];
  __shared__ int s_negc, s_nsel, s_bbin, s_cbef;

  int nc = cand_cnt[row];
  bool fallback = (npos > PCAP) || (nc > CCAP);

  // hoisted item load + norm (wave 0), overlapped with pos/cand LDS fills
  float iv = 0.f;
  if (t < D) iv = item[(size_t)row * D + t];
  if (!fallback) {
    for (int i = t; i < npos; i += 128) s_pos[i] = pos_idx[(size_t)row * PCAP + i];
    for (int i = t; i < nc; i += 128) {
      s_ci[i] = cand_idx[(size_t)row * CCAP + i];
      s_ck[i] = cand_key[(size_t)row * CCAP + i];
    }
  }
  if (t < 64) {
    float ss = iv * iv;
#pragma unroll
    for (int off = 32; off; off >>= 1) ss += __shfl_xor(ss, off, 64);
    s_itemn[t] = iv * (1.0f / sqrtf(ss)) * (1.0f / 0.07f);
  }
  if (t == 0) { s_negc = 0; s_nsel = 0; }
  __syncthreads();

  if (!fallback) {
    // sentinel-out candidates that are positives (cand stream is adj-blind)
    for (int i = t; i < nc; i += 128) {
      int e = s_ci[i];
      bool isPos = false;
      for (int p = 0; p < npos; ++p) isPos |= (s_pos[p] == e);
      if (isPos) s_ck[i] = 0xFFFFFFFFu;
      else atomicAdd(&s_negc, 1);
    }
    __syncthreads();
    if (s_negc < k) fallback = true;  // k-th smallest not guaranteed in bin 0
  }

  // threefry params for this row
  const unsigned HALF = (unsigned)(I >> 1) * (unsigned)E;
  const bool hi = (row >= (I >> 1));
  const unsigned base = (unsigned)(hi ? row - (I >> 1) : row) * (unsigned)E;

  if (!fallback) {
    // exact rank among bin-0 candidates, stable tie-break (key, idx)
    for (int i = t; i < nc; i += 128) {
      unsigned mk = s_ck[i];
      if (mk == 0xFFFFFFFFu) continue;
      int mi = s_ci[i];
      int rank = 0;
      for (int c = 0; c < nc; ++c) {
        unsigned ck = s_ck[c];
        int ci = s_ci[c];
        rank += (ck < mk || (ck == mk && ci < mi)) ? 1 : 0;
      }
      if (rank < k) {
        int s = atomicAdd(&s_nsel, 1);
        if (s < SELCAP) s_sel[s] = mi;
      }
    }
    __syncthreads();
  } else {
    // ---- rare exact fallback: full row rescan with 256-bin histogram ----
    s_hist[t] = 0; s_hist[t + 128] = 0;
    if (t == 0) { s_negc = 0; s_nsel = 0; }
    __syncthreads();
    const int* adjR = adj + (size_t)row * E;
    for (int e = t; e < E; e += 128) {
      if (adjR[e] > 0) continue;
      unsigned o0, o1;
      threefry2x32(base + (unsigned)e, base + (unsigned)e + HALF, o0, o1);
      atomicAdd(&s_hist[(hi ? o1 : o0) >> 24], 1);
    }
    __syncthreads();
    if (t == 0) {
      int cum = 0, b = 0;
      while (b < 255 && cum + s_hist[b] < k) { cum += s_hist[b]; ++b; }
      s_bbin = b; s_cbef = cum;
    }
    __syncthreads();
    const int b = s_bbin;
    for (int e = t; e < E; e += 128) {
      if (adjR[e] > 0) continue;
      unsigned o0, o1;
      threefry2x32(base + (unsigned)e, base + (unsigned)e + HALF, o0, o1);
      unsigned bits = hi ? o1 : o0;
      int b8 = (int)(bits >> 24);
      if (b8 < b) {
        int s = atomicAdd(&s_nsel, 1);
        if (s < SELCAP) s_sel[s] = e;
      } else if (b8 == b) {
        int s = atomicAdd(&s_negc, 1);
        if (s < CCAP) { s_ci[s] = e; s_ck[s] = bits >> 9; }
      }
    }
    __syncthreads();
    const int ncf = min(s_negc, CCAP);
    const int rneed = k - s_cbef;
    for (int i = t; i < ncf; i += 128) {
      unsigned mk = s_ck[i];
      int mi = s_ci[i];
      int rank = 0;
      for (int c = 0; c < ncf; ++c) {
        unsigned ck = s_ck[c];
        int ci = s_ci[c];
        rank += (ck < mk || (ck == mk && ci < mi)) ? 1 : 0;
      }
      if (rank < rneed) {
        int s = atomicAdd(&s_nsel, 1);
        if (s < SELCAP) s_sel[s] = mi;
      }
    }
    __syncthreads();
  }

  const int nsel = min(s_nsel, SELCAP);  // == k

  float myv = (t < nsel) ? dot_sim(ent, s_sel[t], s_itemn) : -INFINITY;
  const float m = bmax128(myv, s_w2, t);
  float v2 = (t < nsel) ? expf(myv - m) : 0.f;
  const float S = bsum128(v2, s_w2, t);

  float lp = 0.f;
  if (!fallback) {
    if (t < npos) {
      float sp = dot_sim(ent, s_pos[t], s_itemn);
      float pm = fmaxf(sp, m);
      lp = logf(expf(sp - pm) + S * expf(m - pm)) + pm - sp;
    }
  } else {
    const int* adjR = adj + (size_t)row * E;
    for (int e = t; e < E; e += 128) {
      if (adjR[e] > 0) {
        float sp = dot_sim(ent, e, s_itemn);
        float pm = fmaxf(sp, m);
        lp += logf(expf(sp - pm) + S * expf(m - pm)) + pm - sp;
      }
    }
  }
  const float rowloss = bsum128(lp, s_w2, t);
  if (t == 0) loss[row] = rowloss;
}

// Deterministic single-block tree reduction: out = sum(loss)/sum(npos).
__global__ __launch_bounds__(256) void reduce_out(
    const float* __restrict__ loss, const int* __restrict__ pos_cnt, int I,
    float* __restrict__ out) {
  const int t = threadIdx.x;
  __shared__ double s_l[256];
  __shared__ int s_n[256];
  double l = 0.0;
  int n = 0;
  for (int i = t; i < I; i += 256) {
    l += (double)loss[i];
    int np = pos_cnt[i];
    if (np > 0) n += np;
  }
  s_l[t] = l; s_n[t] = n;
  __syncthreads();
  for (int off = 128; off; off >>= 1) {
    if (t < off) { s_l[t] += s_l[t + off]; s_n[t] += s_n[t + off]; }
    __syncthreads();
  }
  if (t == 0) out[0] = (s_n[0] > 0) ? (float)(s_l[0] / (double)s_n[0]) : 0.f;
}

// ---------------- monolithic fallback (R2) if ws too small ----------------

__global__ __launch_bounds__(256) void infonce_mono(
    const float* __restrict__ item, const float* __restrict__ ent,
    const int* __restrict__ adj, int I, int E,
    double* __restrict__ accum, int* __restrict__ paircnt) {
  const int t = threadIdx.x;
  const int halfI = I >> 1;
  const int iA = blockIdx.x;
  const int iB = iA + halfI;
  const unsigned HALF = (unsigned)halfI * (unsigned)E;
  const unsigned baseA = (unsigned)iA * (unsigned)E;

  __shared__ int s_pos[2][PCAP];
  __shared__ int s_cidx[2][CCAP];
  __shared__ unsigned s_ckey[2][CCAP];
  __shared__ int s_sel[SELCAP];
  __shared__ int s_hist[256];
  __shared__ float s_itemn[D];
  __shared__ float s_wred[4];
  __shared__ int s_np[2], s_nc[2];
  __shared__ int s_nsel, s_bbin, s_cbef, s_fnc;
  __shared__ float s_scale;

  if (t < 2) { s_np[t] = 0; s_nc[t] = 0; }
  __syncthreads();

  const int nvec = E >> 2;
  const int4* adjA = (const int4*)(adj + (size_t)iA * E);
  const int4* adjB = (const int4*)(adj + (size_t)iB * E);
  for (int v = t; v < nvec; v += 256) {
    int4 a4 = adjA[v];
    int4 b4 = adjB[v];
    int av[4] = {a4.x, a4.y, a4.z, a4.w};
    int bv[4] = {b4.x, b4.y, b4.z, b4.w};
    unsigned e0 = (unsigned)v * 4u;
#pragma unroll
    for (int c = 0; c < 4; ++c) {
      unsigned o0, o1;
      threefry2x32(baseA + e0 + c, baseA + e0 + c + HALF, o0, o1);
      const int e = (int)(e0 + c);
      if (av[c] > 0) {
        int s = atomicAdd(&s_np[0], 1); if (s < PCAP) s_pos[0][s] = e;
      } else if ((o0 >> 24) == 0u) {
        int s = atomicAdd(&s_nc[0], 1);
        if (s < CCAP) { s_cidx[0][s] = e; s_ckey[0][s] = o0 >> 9; }
      }
      if (bv[c] > 0) {
        int s = atomicAdd(&s_np[1], 1); if (s < PCAP) s_pos[1][s] = e;
      } else if ((o1 >> 24) == 0u) {
        int s = atomicAdd(&s_nc[1], 1);
        if (s < CCAP) { s_cidx[1][s] = e; s_ckey[1][s] = o1 >> 9; }
      }
    }
  }
  __syncthreads();

  for (int r2 = 0; r2 < 2; ++r2) {
    const int row = r2 ? iB : iA;
    const int npos = min(s_np[r2], PCAP);
    const int k = min(npos, E - npos);
    if (npos > 0 && k > 0) {
      if (t == 0) s_nsel = 0;
      __syncthreads();
      int ncand = min(s_nc[r2], CCAP);
      int rneed = k;
      if (ncand < k) {
        s_hist[t] = 0;
        if (t == 0) s_fnc = 0;
        __syncthreads();
        const int* adjR = adj + (size_t)row * E;
        for (int e = t; e < E; e += 256) {
          if (adjR[e] > 0) continue;
          unsigned o0, o1;
          threefry2x32(baseA + (unsigned)e, baseA + (unsigned)e + HALF, o0, o1);
          atomicAdd(&s_hist[(r2 ? o1 : o0) >> 24], 1);
        }
        __syncthreads();
        if (t == 0) {
          int cum = 0, b = 0;
          while (b < 255 && cum + s_hist[b] < k) { cum += s_hist[b]; ++b; }
          s_bbin = b; s_cbef = cum;
        }
        __syncthreads();
        const int b = s_bbin;
        for (int e = t; e < E; e += 256) {
          if (adjR[e] > 0) continue;
          unsigned o0, o1;
          threefry2x32(baseA + (unsigned)e, baseA + (unsigned)e + HALF, o0, o1);
          unsigned bits = r2 ? o1 : o0;
          int b8 = (int)(bits >> 24);
          if (b8 < b) {
            int s = atomicAdd(&s_nsel, 1); if (s < SELCAP) s_sel[s] = e;
          } else if (b8 == b) {
            int s = atomicAdd(&s_fnc, 1);
            if (s < CCAP) { s_cidx[r2][s] = e; s_ckey[r2][s] = bits >> 9; }
          }
        }
        __syncthreads();
        ncand = min(s_fnc, CCAP);
        rneed = k - s_cbef;
      }
      for (int c0 = t; c0 < ncand; c0 += 256) {
        unsigned mykey = s_ckey[r2][c0];
        int myidx = s_cidx[r2][c0];
        int rank = 0;
        for (int c = 0; c < ncand; ++c) {
          unsigned ck = s_ckey[r2][c];
          int ci = s_cidx[r2][c];
          rank += (ck < mykey || (ck == mykey && ci < myidx)) ? 1 : 0;
        }
        if (rank < rneed) {
          int s = atomicAdd(&s_nsel, 1); if (s < SELCAP) s_sel[s] = myidx;
        }
      }
      float iv = 0.f;
      if (t < D) iv = item[(size_t)row * D + t];
      if (t < 64) {
        float ss = iv * iv;
#pragma unroll
        for (int off = 32; off; off >>= 1) ss += __shfl_xor(ss, off, 64);
        if (t == 0) s_scale = (1.0f / sqrtf(ss)) * (1.0f / 0.07f);
      }
      __syncthreads();
      if (t < D) s_itemn[t] = iv * s_scale;
      __syncthreads();
      const int nsel = min(s_nsel, SELCAP);
      float myv = (t < nsel) ? dot_sim(ent, s_sel[t], s_itemn) : -INFINITY;
#pragma unroll
      for (int off = 32; off; off >>= 1) myv = fmaxf(myv, __shfl_xor(myv, off, 64));
      __syncthreads();
      if ((t & 63) == 0) s_wred[t >> 6] = myv;
      __syncthreads();
      const float m = fmaxf(fmaxf(s_wred[0], s_wred[1]), fmaxf(s_wred[2], s_wred[3]));
      float myv2 = (t < nsel) ? dot_sim(ent, s_sel[t], s_itemn) : -INFINITY;
      float v2 = (t < nsel) ? expf(myv2 - m) : 0.f;
#pragma unroll
      for (int off = 32; off; off >>= 1) v2 += __shfl_xor(v2, off, 64);
      __syncthreads();
      if ((t & 63) == 0) s_wred[t >> 6] = v2;
      __syncthreads();
      const float S = s_wred[0] + s_wred[1] + s_wred[2] + s_wred[3];
      float lp = 0.f;
      if (t < npos) {
        float sp = dot_sim(ent, s_pos[r2][t], s_itemn);
        float pm = fmaxf(sp, m);
        lp = logf(expf(sp - pm) + S * expf(m - pm)) + pm - sp;
      }
#pragma unroll
      for (int off = 32; off; off >>= 1) lp += __shfl_xor(lp, off, 64);
      __syncthreads();
      if ((t & 63) == 0) s_wred[t >> 6] = lp;
      __syncthreads();
      const float rowloss = s_wred[0] + s_wred[1] + s_wred[2] + s_wred[3];
      if (t == 0) {
        atomicAdd(accum, (double)rowloss);
        atomicAdd(paircnt, npos);
      }
      __syncthreads();
    }
  }
}

__global__ void infonce_init(double* accum, int* cnt) {
  if (threadIdx.x == 0 && blockIdx.x == 0) { accum[0] = 0.0; cnt[0] = 0; }
}

__global__ void infonce_final(const double* __restrict__ accum,
                              const int* __restrict__ cnt,
                              float* __restrict__ out) {
  if (threadIdx.x == 0 && blockIdx.x == 0) {
    int n = cnt[0];
    out[0] = (n > 0) ? (float)(accum[0] / (double)n) : 0.f;
  }
}

extern "C" void kernel_launch(void* const* d_in, const int* in_sizes, int n_in,
                              void* d_out, int out_size, void* d_ws, size_t ws_size,
                              hipStream_t stream) {
  const float* item = (const float*)d_in[0];
  const float* ent  = (const float*)d_in[1];
  const int*   adj  = (const int*)d_in[2];
  const int I = in_sizes[0] / D;   // 4096
  const int E = in_sizes[1] / D;   // 16384

  const size_t need = 16 + (size_t)I * 4 * 3 + (size_t)I * PCAP * 4 +
                      (size_t)I * CCAP * 8;
  if (ws_size >= need && (I % 2) == 0) {
    int*      pos_cnt  = (int*)((char*)d_ws + 16);
    int*      cand_cnt = pos_cnt + I;
    float*    loss     = (float*)(cand_cnt + I);
    int*      pos_idx  = (int*)(loss + I);
    int*      cand_idx = pos_idx + (size_t)I * PCAP;
    unsigned* cand_key = (unsigned*)(cand_idx + (size_t)I * CCAP);

    ws_zero<<<(I + 255) / 256, 256, 0, stream>>>(pos_cnt, cand_cnt, loss, I);
    phase1<<<I + I / 2, 256, 0, stream>>>(adj, I, E, pos_cnt, pos_idx,
                                          cand_cnt, cand_idx, cand_key);
    finalize<<<I, 128, 0, stream>>>(item, ent, adj, I, E, pos_cnt, pos_idx,
                                    cand_cnt, cand_idx, cand_key, loss);
    reduce_out<<<1, 256, 0, stream>>>(loss, pos_cnt, I, (float*)d_out);
  } else {
    double* accum   = (double*)d_ws;
    int*    paircnt = (int*)((char*)d_ws + 8);
    infonce_init<<<1, 64, 0, stream>>>(accum, paircnt);
    infonce_mono<<<I / 2, 256, 0, stream>>>(item, ent, adj, I, E, accum, paircnt);
    infonce_final<<<1, 64, 0, stream>>>(accum, paircnt, (float*)d_out);
  }
}

// Round 5
// 156.332 us; speedup vs baseline: 2.0674x; 2.0674x over previous
//
#include <hip/hip_runtime.h>
#include <math.h>

// InfoNCE, exact JAX threefry2x32 negative-sampling reproduction.
// I=4096, E=16384, D=64.
//
// R5: revert to the R2 monolith (best measured: 188us; the R3/R4 split's
// standalone finalize kernel was anomalously slow and is abandoned).
// Changes vs R2:
//  - ballot-based wave appends (one leader LDS atomic + mbcnt offsets,
//    uniform skip when no lane matches) instead of per-lane
//    atomicAdd->wait->store chains (R2's VALUBusy was only 42%).
//  - all 4 threefry evals computed straight-line before any append (ILP).
//  - nontemporal adj loads (one-shot 256MB stream; keep L2 for ent).
//  - per-row loss/cnt arrays + deterministic single-block reduce
//    (no same-address f64 atomics; no pre-zero needed).

constexpr int D      = 64;
constexpr int PCAP   = 96;    // num_pos ~ Binom(16384,.002): mean 33
constexpr int CCAP   = 192;   // bin-0 negs ~ Binom(16384,1/256): mean 64
constexpr int SELCAP = 128;   // k <= npos <= PCAP

typedef int int4v __attribute__((ext_vector_type(4)));

// JAX threefry2x32, key = (0, 42) from jax.random.key(42).
__device__ __forceinline__ void threefry2x32(unsigned x0, unsigned x1,
                                             unsigned& o0, unsigned& o1) {
  const unsigned ks0 = 0u;
  const unsigned ks1 = 42u;
  const unsigned ks2 = 0x1BD11BDAu ^ 0u ^ 42u;
  x0 += ks0; x1 += ks1;
#define TF_R(r) { x0 += x1; x1 = (x1 << (r)) | (x1 >> (32 - (r))); x1 ^= x0; }
  TF_R(13) TF_R(15) TF_R(26) TF_R(6)
  x0 += ks1; x1 += ks2 + 1u;
  TF_R(17) TF_R(29) TF_R(16) TF_R(24)
  x0 += ks2; x1 += ks0 + 2u;
  TF_R(13) TF_R(15) TF_R(26) TF_R(6)
  x0 += ks0; x1 += ks1 + 3u;
  TF_R(17) TF_R(29) TF_R(16) TF_R(24)
  x0 += ks1; x1 += ks2 + 4u;
  TF_R(13) TF_R(15) TF_R(26) TF_R(6)
  x0 += ks2; x1 += ks0 + 5u;
#undef TF_R
  o0 = x0; o1 = x1;
}

__device__ __forceinline__ float dot_sim(const float* __restrict__ ent, int e,
                                         const float* itemn) {
  const float4* er = (const float4*)(ent + ((size_t)e << 6));
  float dot = 0.f, ss = 0.f;
#pragma unroll
  for (int q = 0; q < 16; ++q) {
    float4 f = er[q];
    dot += itemn[4 * q + 0] * f.x + itemn[4 * q + 1] * f.y +
           itemn[4 * q + 2] * f.z + itemn[4 * q + 3] * f.w;
    ss += f.x * f.x + f.y * f.y + f.z * f.z + f.w * f.w;
  }
  return dot * (1.0f / sqrtf(ss));
}

// wave-cooperative list append: one leader atomic, mbcnt offsets.
// Uniform-skips entirely when no lane matches (the common case).
__device__ __forceinline__ void wave_append(bool pred, int e,
                                            int* cnt, int* list, int cap) {
  unsigned long long m = __ballot(pred);
  if (m) {
    const int lane = threadIdx.x & 63;
    const int leader = __builtin_ctzll(m);
    int base = 0;
    if (lane == leader) base = atomicAdd(cnt, __popcll(m));
    base = __shfl(base, leader, 64);
    if (pred) {
      int s = base + __popcll(m & ((1ull << lane) - 1ull));
      if (s < cap) list[s] = e;
    }
  }
}

__device__ __forceinline__ void wave_append2(bool pred, int e, unsigned key,
                                             int* cnt, int* li, unsigned* lk,
                                             int cap) {
  unsigned long long m = __ballot(pred);
  if (m) {
    const int lane = threadIdx.x & 63;
    const int leader = __builtin_ctzll(m);
    int base = 0;
    if (lane == leader) base = atomicAdd(cnt, __popcll(m));
    base = __shfl(base, leader, 64);
    if (pred) {
      int s = base + __popcll(m & ((1ull << lane) - 1ull));
      if (s < cap) { li[s] = e; lk[s] = key; }
    }
  }
}

__device__ __forceinline__ float block_max(float v, float* wred, int t) {
#pragma unroll
  for (int off = 32; off; off >>= 1) v = fmaxf(v, __shfl_xor(v, off, 64));
  __syncthreads();
  if ((t & 63) == 0) wred[t >> 6] = v;
  __syncthreads();
  return fmaxf(fmaxf(wred[0], wred[1]), fmaxf(wred[2], wred[3]));
}

__device__ __forceinline__ float block_sum(float v, float* wred, int t) {
#pragma unroll
  for (int off = 32; off; off >>= 1) v += __shfl_xor(v, off, 64);
  __syncthreads();
  if ((t & 63) == 0) wred[t >> 6] = v;
  __syncthreads();
  return wred[0] + wred[1] + wred[2] + wred[3];
}

// One block per row pair (iA, iA+I/2): element j of row iA is out0 of
// threefry(j_glob, j_glob+2^25); row iB's element j is out1 of the SAME eval.
// WSOUT=true: write per-row loss/cnt arrays; false: f64 global atomics.
template <bool WSOUT>
__global__ __launch_bounds__(256) void infonce_mono(
    const float* __restrict__ item, const float* __restrict__ ent,
    const int* __restrict__ adj, int I, int E,
    float* __restrict__ loss, int* __restrict__ cnt,
    double* __restrict__ accum, int* __restrict__ paircnt) {
  const int t = threadIdx.x;
  const int halfI = I >> 1;
  const int iA = blockIdx.x;
  const int iB = iA + halfI;
  const unsigned HALF = (unsigned)halfI * (unsigned)E;  // 2^25
  const unsigned baseA = (unsigned)iA * (unsigned)E;

  __shared__ int s_pos[2][PCAP];
  __shared__ int s_ci[2][CCAP];
  __shared__ unsigned s_ck[2][CCAP];
  __shared__ int s_sel[SELCAP];
  __shared__ int s_hist[256];
  __shared__ float s_itemn[D];
  __shared__ float s_wred[4];
  __shared__ int s_np[2], s_nc[2];
  __shared__ int s_nsel, s_bbin, s_cbef, s_fnc;
  __shared__ float s_scale;

  if (t < 2) { s_np[t] = 0; s_nc[t] = 0; }
  __syncthreads();

  // ---- Phase 1: fused adj stream + threefry + ballot appends ----
  const int nvec = E >> 2;
  const int4v* adjA = (const int4v*)(adj + (size_t)iA * E);
  const int4v* adjB = (const int4v*)(adj + (size_t)iB * E);
  for (int v = t; v < nvec; v += 256) {
    int4v a4 = __builtin_nontemporal_load(&adjA[v]);
    int4v b4 = __builtin_nontemporal_load(&adjB[v]);
    const unsigned e0 = (unsigned)v * 4u;
    unsigned o0[4], o1[4];
#pragma unroll
    for (int c = 0; c < 4; ++c)  // straight-line: 4 independent evals
      threefry2x32(baseA + e0 + c, baseA + e0 + c + HALF, o0[c], o1[c]);
#pragma unroll
    for (int c = 0; c < 4; ++c) {
      const int e = (int)(e0 + c);
      const bool pa = (a4[c] > 0), pb = (b4[c] > 0);
      wave_append(pa, e, &s_np[0], s_pos[0], PCAP);
      wave_append(pb, e, &s_np[1], s_pos[1], PCAP);
      wave_append2(!pa && (o0[c] >> 24) == 0u, e, o0[c] >> 9,
                   &s_nc[0], s_ci[0], s_ck[0], CCAP);
      wave_append2(!pb && (o1[c] >> 24) == 0u, e, o1[c] >> 9,
                   &s_nc[1], s_ci[1], s_ck[1], CCAP);
    }
  }
  __syncthreads();

  // ---- Phase 2: per-row selection + loss ----
  for (int r2 = 0; r2 < 2; ++r2) {
    const int row = r2 ? iB : iA;
    const int npos = min(s_np[r2], PCAP);
    const int k = min(npos, E - npos);  // NEG_RATIO = 1.0
    const bool valid = (npos > 0 && k > 0);  // block-uniform
    float rowloss = 0.f;
    if (valid) {
      if (t == 0) s_nsel = 0;
      __syncthreads();
      int ncand = min(s_nc[r2], CCAP);  // all candidates are negatives
      int rneed = k;
      if (s_nc[r2] > CCAP || ncand < k) {
        // ---- rare exact fallback: full row rescan, 256-bin histogram ----
        s_hist[t] = 0;
        if (t == 0) s_fnc = 0;
        __syncthreads();
        const int* adjR = adj + (size_t)row * E;
        for (int e = t; e < E; e += 256) {
          if (adjR[e] > 0) continue;
          unsigned o0, o1;
          threefry2x32(baseA + (unsigned)e, baseA + (unsigned)e + HALF, o0, o1);
          atomicAdd(&s_hist[(r2 ? o1 : o0) >> 24], 1);
        }
        __syncthreads();
        if (t == 0) {
          int cum = 0, b = 0;
          while (b < 255 && cum + s_hist[b] < k) { cum += s_hist[b]; ++b; }
          s_bbin = b; s_cbef = cum;
        }
        __syncthreads();
        const int b = s_bbin;
        for (int e = t; e < E; e += 256) {
          bool neg = (adjR[e] <= 0);
          unsigned o0, o1, bits = 0xFFFFFFFFu;
          if (neg) {
            threefry2x32(baseA + (unsigned)e, baseA + (unsigned)e + HALF, o0, o1);
            bits = r2 ? o1 : o0;
          }
          int b8 = (int)(bits >> 24);
          wave_append(neg && b8 < b, e, &s_nsel, s_sel, SELCAP);
          wave_append2(neg && b8 == b, e, bits >> 9,
                       &s_fnc, s_ci[r2], s_ck[r2], CCAP);
        }
        __syncthreads();
        ncand = min(s_fnc, CCAP);
        rneed = k - s_cbef;
      }

      // exact rank among candidates, stable tie-break (key, idx)
      for (int i = t; i < ncand; i += 256) {
        const unsigned mk = s_ck[r2][i];
        const int mi = s_ci[r2][i];
        int rank = 0;
        for (int c = 0; c < ncand; ++c) {
          const unsigned ck = s_ck[r2][c];
          const int ci = s_ci[r2][c];
          rank += (ck < mk || (ck == mk && ci < mi)) ? 1 : 0;
        }
        if (rank < rneed) {
          int s = atomicAdd(&s_nsel, 1);
          if (s < SELCAP) s_sel[s] = mi;
        }
      }

      // item row scale = 1/||item|| / T
      float iv = 0.f;
      if (t < D) iv = item[(size_t)row * D + t];
      if (t < 64) {
        float ss = iv * iv;
#pragma unroll
        for (int off = 32; off; off >>= 1) ss += __shfl_xor(ss, off, 64);
        if (t == 0) s_scale = (1.0f / sqrtf(ss)) * (1.0f / 0.07f);
      }
      __syncthreads();  // also closes the rank-append section
      if (t < D) s_itemn[t] = iv * s_scale;
      __syncthreads();
      const int nsel = min(s_nsel, SELCAP);  // == k

      float myv = (t < nsel) ? dot_sim(ent, s_sel[t], s_itemn) : -INFINITY;
      const float m = block_max(myv, s_wred, t);
      float v2 = (t < nsel) ? expf(myv - m) : 0.f;  // register reuse, no 2nd dot
      const float S = block_sum(v2, s_wred, t);

      float lp = 0.f;
      if (t < npos) {
        float sp = dot_sim(ent, s_pos[r2][t], s_itemn);
        float pm = fmaxf(sp, m);
        lp = logf(expf(sp - pm) + S * expf(m - pm)) + pm - sp;
      }
      rowloss = block_sum(lp, s_wred, t);
    }
    if (WSOUT) {
      if (t == 0) { loss[row] = valid ? rowloss : 0.f; cnt[row] = valid ? npos : 0; }
    } else {
      if (valid && t == 0) {
        atomicAdd(accum, (double)rowloss);
        atomicAdd(paircnt, npos);
      }
    }
    __syncthreads();
  }
}

// Deterministic single-block tree reduction: out = sum(loss)/sum(cnt).
__global__ __launch_bounds__(256) void reduce_out(
    const float* __restrict__ loss, const int* __restrict__ cnt, int I,
    float* __restrict__ out) {
  const int t = threadIdx.x;
  __shared__ double s_l[256];
  __shared__ int s_n[256];
  double l = 0.0;
  int n = 0;
  for (int i = t; i < I; i += 256) { l += (double)loss[i]; n += cnt[i]; }
  s_l[t] = l; s_n[t] = n;
  __syncthreads();
  for (int off = 128; off; off >>= 1) {
    if (t < off) { s_l[t] += s_l[t + off]; s_n[t] += s_n[t + off]; }
    __syncthreads();
  }
  if (t == 0) out[0] = (s_n[0] > 0) ? (float)(s_l[0] / (double)s_n[0]) : 0.f;
}

__global__ void infonce_init(double* accum, int* cnt) {
  if (threadIdx.x == 0 && blockIdx.x == 0) { accum[0] = 0.0; cnt[0] = 0; }
}

__global__ void infonce_final(const double* __restrict__ accum,
                              const int* __restrict__ cnt,
                              float* __restrict__ out) {
  if (threadIdx.x == 0 && blockIdx.x == 0) {
    int n = cnt[0];
    out[0] = (n > 0) ? (float)(accum[0] / (double)n) : 0.f;
  }
}

extern "C" void kernel_launch(void* const* d_in, const int* in_sizes, int n_in,
                              void* d_out, int out_size, void* d_ws, size_t ws_size,
                              hipStream_t stream) {
  const float* item = (const float*)d_in[0];
  const float* ent  = (const float*)d_in[1];
  const int*   adj  = (const int*)d_in[2];
  const int I = in_sizes[0] / D;   // 4096
  const int E = in_sizes[1] / D;   // 16384

  const size_t need = (size_t)I * 8;  // loss[I] f32 + cnt[I] i32
  if (ws_size >= need && (I % 2) == 0) {
    float* loss = (float*)d_ws;
    int*   cnt  = (int*)(loss + I);
    infonce_mono<true><<<I / 2, 256, 0, stream>>>(item, ent, adj, I, E,
                                                  loss, cnt, nullptr, nullptr);
    reduce_out<<<1, 256, 0, stream>>>(loss, cnt, I, (float*)d_out);
  } else {
    double* accum   = (double*)d_ws;
    int*    paircnt = (int*)((char*)d_ws + 8);
    infonce_init<<<1, 64, 0, stream>>>(accum, paircnt);
    infonce_mono<false><<<I / 2, 256, 0, stream>>>(item, ent, adj, I, E,
                                                   nullptr, nullptr, accum, paircnt);
    infonce_final<<<1, 64, 0, stream>>>(accum, paircnt, (float*)d_out);
  }
}